// Round 11
// baseline (209.071 us; speedup 1.0000x reference)
//
#include <hip/hip_runtime.h>
#include <hip/hip_bf16.h>

typedef __attribute__((ext_vector_type(4))) float f32x4;
typedef __attribute__((ext_vector_type(2))) _Float16 h2;
typedef __attribute__((ext_vector_type(8))) _Float16 f16x8;

// ---------------- x [2][256][4096] f32 -> x16h [2][4096][256] f16 (HWC) ----------------
__global__ __launch_bounds__(256) void transpose_x_hwc_f16(const float* __restrict__ x,
                                                           unsigned short* __restrict__ x16h) {
    __shared__ float s[64][65];
    int blk = blockIdx.x;                 // 2 b * 4 ct * 64 pt = 512
    int b = blk >> 8, ct = (blk >> 6) & 3, pt = blk & 63;
    int c0 = ct * 64, p0 = pt * 64;
    int tid = threadIdx.x;
    int tr = tid >> 6, tc = tid & 63;
#pragma unroll
    for (int i = 0; i < 16; ++i) {
        int c = i * 4 + tr;
        s[c][tc] = x[((size_t)b * 256 + c0 + c) * 4096 + p0 + tc];
    }
    __syncthreads();
#pragma unroll
    for (int i = 0; i < 16; ++i) {
        int pp = i * 4 + tr;
        _Float16 h = (_Float16)s[tc][pp];
        x16h[((size_t)b * 4096 + p0 + pp) * 256 + c0 + tc] = *(unsigned short*)&h;
    }
}

// dweights [4][256][256][3][3] fp32 -> wTh [i][k][o][c] f16
__global__ __launch_bounds__(256) void transpose_dw_f16(const float* __restrict__ dw,
                                                        unsigned short* __restrict__ wTh) {
    int idx = blockIdx.x * 256 + threadIdx.x;      // 2359296
    int c = idx & 255;
    int o = (idx >> 8) & 255;
    int rest = idx >> 16;
    int k = rest % 9, i = rest / 9;
    _Float16 h = (_Float16)dw[(((i << 8) + o) * 256 + c) * 9 + k];
    wTh[idx] = *(unsigned short*)&h;
}

// oweights [4][18][256][3][3] fp32 -> owTh [r][k][32][256] f16 (rows 18..31 zero)
__global__ __launch_bounds__(256) void transpose_ow_f16(const float* __restrict__ ow,
                                                        unsigned short* __restrict__ owTh) {
    int idx = blockIdx.x * 256 + threadIdx.x;      // 294912
    int c = idx & 255;
    int m = (idx >> 8) & 31;
    int rk = idx >> 13;
    int k = rk % 9, r = rk / 9;
    float v = (m < 18) ? ow[((r * 18 + m) * 256 + c) * 9 + k] : 0.f;
    _Float16 h = (_Float16)v;
    owTh[idx] = *(unsigned short*)&h;
}

// ---------------- offset conv v2: f16 HWC dense staging + prefetch (r10, verified) ----------------
__global__ __launch_bounds__(512) void offset_mfma2f(const unsigned short* __restrict__ x16h,
                                                     const unsigned short* __restrict__ owTh,
                                                     const float* __restrict__ obias,
                                                     float* __restrict__ off) {
    __shared__ short    s_a[4][32][8];
    __shared__ short    s_b[4][128][8];
    __shared__ int      s_pix[9][128];
    __shared__ unsigned s_msk[9][128];

    const int blk = blockIdx.x;
    const int r = (blk & 7) >> 1, b = blk & 1;
    const int px0 = (blk >> 3) << 7;
    const int rate = 6 * (r + 1);

    const int tid = threadIdx.x;
    const int lane = tid & 63;
    const int w = tid >> 6;
    const int kg = lane >> 4, lm = lane & 15;
    const int sg = tid >> 7, spx = tid & 127;
    const int mA = (tid & 127) >> 2, kgA = tid & 3;

    const unsigned short* xbh = x16h + (size_t)b * 1048576;
    const unsigned short* wrb = owTh + (size_t)r * 9 * 32 * 256;

    for (int e = tid; e < 1152; e += 512) {
        int k = e >> 7, pl = e & 127;
        int pg = px0 + pl;
        int yy = (pg >> 6) + (k / 3 - 1) * rate;
        int xx = (pg & 63) + (k % 3 - 1) * rate;
        bool v = ((unsigned)yy < 64u) && ((unsigned)xx < 64u);
        int cy = min(max(yy, 0), 63), cx = min(max(xx, 0), 63);
        s_pix[k][pl] = cy * 64 + cx;
        s_msk[k][pl] = v ? 0xFFFFFFFFu : 0u;
    }
    __syncthreads();

    f32x4 acc0 = (f32x4)(0.f), acc1 = (f32x4)(0.f);

    uint4 a, v;
    if (tid < 128) a = *(const uint4*)(wrb + (size_t)mA * 256 + kgA * 8);
    {
        int pix = s_pix[0][spx];
        v = *(const uint4*)(xbh + (size_t)pix * 256 + sg * 8);
    }
    unsigned m = s_msk[0][spx];

    for (int t = 0; t < 72; ++t) {
        uint4 pk = make_uint4(v.x & m, v.y & m, v.z & m, v.w & m);

        __syncthreads();
        if (tid < 128) *(uint4*)&s_a[kgA][mA][0] = a;
        *(uint4*)&s_b[sg][spx][0] = pk;
        __syncthreads();

        if (t < 71) {
            int tn = t + 1, tapn = tn >> 3, c0n = (tn & 7) << 5;
            if (tid < 128)
                a = *(const uint4*)(wrb + ((size_t)tapn * 32 + mA) * 256 + c0n + kgA * 8);
            int pix = s_pix[tapn][spx];
            m = s_msk[tapn][spx];
            v = *(const uint4*)(xbh + (size_t)pix * 256 + c0n + sg * 8);
        }

        f16x8 bf  = *(const f16x8*)&s_b[kg][w * 16 + lm][0];
        f16x8 af0 = *(const f16x8*)&s_a[kg][lm][0];
        f16x8 af1 = *(const f16x8*)&s_a[kg][16 + lm][0];
        acc0 = __builtin_amdgcn_mfma_f32_16x16x32_f16(af0, bf, acc0, 0, 0, 0);
        acc1 = __builtin_amdgcn_mfma_f32_16x16x32_f16(af1, bf, acc1, 0, 0, 0);
    }

    const float* bias = obias + r * 18;
    float* ob = off + (size_t)(r * 2 + b) * 18 * 4096;
    int px = px0 + w * 16 + lm;
#pragma unroll
    for (int reg = 0; reg < 4; ++reg) {
        int mm = kg * 4 + reg;
        ob[(size_t)mm * 4096 + px] = fmaxf(acc0[reg] + bias[mm], 0.f);
        int m1 = 16 + mm;
        if (m1 < 18)
            ob[(size_t)m1 * 4096 + px] = fmaxf(acc1[reg] + bias[m1], 0.f);
    }
}

// ---------------- deformable conv v8: A direct-to-reg, single raw barrier, dbuf B ----------------
// grid: 512 blocks; blk&7 = (i,b) [one branch per XCD: weights+x L2-resident],
// blk>>3 = 64-px tile. 512 threads = 8 waves; wave = 64o x 32px; K-step 64; 36 steps.
// r10 lesson: __syncthreads' vmcnt(0) drain killed prefetch; LDS A round-trip
// (96KB/block/step) dominated. A fragments now load global->reg (L2-hit, 16B/lane),
// s_b double-buffered, ONE raw barrier (lgkmcnt-only wait) per step.
#define MFMA2(AF, B0, B1, M)                                                            \
    acc[M][0] = __builtin_amdgcn_mfma_f32_16x16x32_f16(*(const f16x8*)&AF, B0, acc[M][0], 0, 0, 0); \
    acc[M][1] = __builtin_amdgcn_mfma_f32_16x16x32_f16(*(const f16x8*)&AF, B1, acc[M][1], 0, 0, 0);

__global__ __launch_bounds__(512, 2) void deform_mfma8(const unsigned short* __restrict__ x16h,
                                                       const unsigned short* __restrict__ wTh,
                                                       const float* __restrict__ off,
                                                       float* __restrict__ out) {
    __shared__ short  s_b[2][64][64];   // [buf][px][oct^(px&7) octets of 8ch]  16 KB
    __shared__ int4   s_pix[9][64];
    __shared__ float4 s_wt[9][64];

    const int blk = blockIdx.x;
    const int i = (blk & 7) >> 1, b = blk & 1;
    const int px0 = (blk >> 3) << 6;
    const int r = (i + 3) & 3;
    const int rate = 6 * (i + 1);

    const int tid = threadIdx.x;
    const int lane = tid & 63;
    const int w = tid >> 6;
    const int wo = w >> 1, wp = w & 1;          // o-quarter (64), px-half (32)
    const int kg = lane >> 4, lm = lane & 15;
    const int pxS = tid >> 3, chgS = tid & 7;   // B staging: pixel, channel-octet

    const unsigned short* xbh = x16h + (size_t)b * 1048576;
    const float* offb = off + (size_t)(r * 2 + b) * 18 * 4096;
    const unsigned short* wib = wTh + (size_t)i * 9 * 65536;
    // per-lane A fragment base: row = wo*64 + lm, col-octet = kg
    const unsigned short* wlane = wib + (size_t)(wo * 64 + lm) * 256 + kg * 8;

    for (int e = tid; e < 576; e += 512) {
        int k = e >> 6, pl = e & 63;
        int pg = px0 + pl;
        int yy = pg >> 6, xc = pg & 63;
        float dy = offb[(size_t)(2 * k) * 4096 + pg];
        float dx = offb[(size_t)(2 * k + 1) * 4096 + pg];
        float py = (float)(yy + (k / 3 - 1) * rate) + dy;
        float pxf = (float)(xc + (k % 3 - 1) * rate) + dx;
        float fy = floorf(py), fx = floorf(pxf);
        int y0 = (int)fy, x0 = (int)fx;
        float wy = py - fy, wx = pxf - fx;
        float vy0 = ((unsigned)y0 < 64u) ? 1.f : 0.f;
        float vy1 = ((unsigned)(y0 + 1) < 64u) ? 1.f : 0.f;
        float vx0 = ((unsigned)x0 < 64u) ? 1.f : 0.f;
        float vx1 = ((unsigned)(x0 + 1) < 64u) ? 1.f : 0.f;
        int cy0 = min(max(y0, 0), 63), cy1 = min(max(y0 + 1, 0), 63);
        int cx0 = min(max(x0, 0), 63), cx1 = min(max(x0 + 1, 0), 63);
        s_pix[k][pl] = make_int4(cy0 * 64 + cx0, cy0 * 64 + cx1,
                                 cy1 * 64 + cx0, cy1 * 64 + cx1);
        s_wt[k][pl] = make_float4(vy0 * vx0 * (1.f - wy) * (1.f - wx),
                                  vy0 * vx1 * (1.f - wy) * wx,
                                  vy1 * vx0 * wy * (1.f - wx),
                                  vy1 * vx1 * wy * wx);
    }
    __syncthreads();

    f32x4 acc[4][2];
#pragma unroll
    for (int mi = 0; mi < 4; ++mi) {
        acc[mi][0] = (f32x4)(0.f);
        acc[mi][1] = (f32x4)(0.f);
    }

    // prologue: loads for t=0
    uint4 a00, a01, a02, a03, a10, a11, a12, a13, v0, v1, v2, v3;
    {
        const unsigned short* wb = wlane;              // tap=0, c0=0
        a00 = *(const uint4*)(wb);
        a01 = *(const uint4*)(wb + 4096);
        a02 = *(const uint4*)(wb + 8192);
        a03 = *(const uint4*)(wb + 12288);
        a10 = *(const uint4*)(wb + 32);
        a11 = *(const uint4*)(wb + 4096 + 32);
        a12 = *(const uint4*)(wb + 8192 + 32);
        a13 = *(const uint4*)(wb + 12288 + 32);
        int4 p = s_pix[0][pxS];
        const unsigned short* xch = xbh + chgS * 8;
        v0 = *(const uint4*)(xch + ((size_t)p.x << 8));
        v1 = *(const uint4*)(xch + ((size_t)p.y << 8));
        v2 = *(const uint4*)(xch + ((size_t)p.z << 8));
        v3 = *(const uint4*)(xch + ((size_t)p.w << 8));
    }

    int buf = 0;
    for (int t = 0; t < 36; ++t) {
        const int tap = t >> 2;

        // lerp current corners (packed f16) -> B fragment
        uint4 pk;
        {
            float4 qwf = s_wt[tap][pxS];
            h2 qx = (h2)((_Float16)qwf.x), qy = (h2)((_Float16)qwf.y);
            h2 qz = (h2)((_Float16)qwf.z), qv = (h2)((_Float16)qwf.w);
            h2 r0 = (*(h2*)&v0.x) * qx + (*(h2*)&v1.x) * qy + (*(h2*)&v2.x) * qz + (*(h2*)&v3.x) * qv;
            h2 r1 = (*(h2*)&v0.y) * qx + (*(h2*)&v1.y) * qy + (*(h2*)&v2.y) * qz + (*(h2*)&v3.y) * qv;
            h2 r2 = (*(h2*)&v0.z) * qx + (*(h2*)&v1.z) * qy + (*(h2*)&v2.z) * qz + (*(h2*)&v3.z) * qv;
            h2 r3 = (*(h2*)&v0.w) * qx + (*(h2*)&v1.w) * qy + (*(h2*)&v2.w) * qz + (*(h2*)&v3.w) * qv;
            pk = make_uint4(*(unsigned*)&r0, *(unsigned*)&r1, *(unsigned*)&r2, *(unsigned*)&r3);
        }
        *(uint4*)&s_b[buf][pxS][(chgS ^ (pxS & 7)) * 8] = pk;

        // raw barrier: wait LDS write only (no vmcnt drain -> prefetch stays in flight)
        asm volatile("s_waitcnt lgkmcnt(0)\n\ts_barrier" ::: "memory");

        if (t < 35) {   // v-corner prefetch for t+1 (v regs dead after lerp)
            int tn = t + 1, tapn = tn >> 2, c0n = (tn & 3) << 6;
            int4 p = s_pix[tapn][pxS];
            const unsigned short* xch = xbh + c0n + chgS * 8;
            v0 = *(const uint4*)(xch + ((size_t)p.x << 8));
            v1 = *(const uint4*)(xch + ((size_t)p.y << 8));
            v2 = *(const uint4*)(xch + ((size_t)p.z << 8));
            v3 = *(const uint4*)(xch + ((size_t)p.w << 8));
        }

        // MFMA phase: B from LDS, A from registers
        {
            int bcol0 = (kg ^ (lm & 7)) * 8;
            int bcol1 = ((kg + 4) ^ (lm & 7)) * 8;
            f16x8 b00 = *(const f16x8*)&s_b[buf][wp * 32 + lm][bcol0];
            f16x8 b01 = *(const f16x8*)&s_b[buf][wp * 32 + 16 + lm][bcol0];
            MFMA2(a00, b00, b01, 0)
            MFMA2(a01, b00, b01, 1)
            MFMA2(a02, b00, b01, 2)
            MFMA2(a03, b00, b01, 3)
            f16x8 b10 = *(const f16x8*)&s_b[buf][wp * 32 + lm][bcol1];
            f16x8 b11 = *(const f16x8*)&s_b[buf][wp * 32 + 16 + lm][bcol1];
            MFMA2(a10, b10, b11, 0)
            MFMA2(a11, b10, b11, 1)
            MFMA2(a12, b10, b11, 2)
            MFMA2(a13, b10, b11, 3)
        }

        if (t < 35) {   // A prefetch for t+1 (A regs dead after MFMA)
            int tn = t + 1, tapn = tn >> 2, c0n = (tn & 3) << 6;
            const unsigned short* wb = wlane + (size_t)tapn * 65536 + c0n;
            a00 = *(const uint4*)(wb);
            a01 = *(const uint4*)(wb + 4096);
            a02 = *(const uint4*)(wb + 8192);
            a03 = *(const uint4*)(wb + 12288);
            a10 = *(const uint4*)(wb + 32);
            a11 = *(const uint4*)(wb + 4096 + 32);
            a12 = *(const uint4*)(wb + 8192 + 32);
            a13 = *(const uint4*)(wb + 12288 + 32);
        }
        buf ^= 1;
    }

    // epilogue: C/D col = lane&15 (px), row = kg*4 + reg (o)
    float* ob = out + ((size_t)b * 1024 + i * 256) * 4096;
#pragma unroll
    for (int mi = 0; mi < 4; ++mi) {
        int o = wo * 64 + mi * 16 + kg * 4;
#pragma unroll
        for (int ni = 0; ni < 2; ++ni) {
            int pg = px0 + wp * 32 + ni * 16 + lm;
#pragma unroll
            for (int reg = 0; reg < 4; ++reg)
                ob[(size_t)(o + reg) * 4096 + pg] = acc[mi][ni][reg];
        }
    }
}

extern "C" void kernel_launch(void* const* d_in, const int* in_sizes, int n_in,
                              void* d_out, int out_size, void* d_ws, size_t ws_size,
                              hipStream_t stream) {
    const float* x  = (const float*)d_in[0];   // [2,256,64,64]
    const float* dw = (const float*)d_in[1];   // [4,256,256,3,3]
    const float* ow = (const float*)d_in[2];   // [4,18,256,3,3]
    const float* ob = (const float*)d_in[3];   // [4,18]
    float* out = (float*)d_out;                // [2,1024,64,64]

    float* ws  = (float*)d_ws;
    float* off = ws;                                        // 589824 f32
    unsigned short* wTh  = (unsigned short*)(ws + 589824);  // 2359296 f16
    unsigned short* owTh = wTh + 2359296;                   // 294912 f16
    unsigned short* x16h = (unsigned short*)(ws + 1916928); // 2097152 f16 [b][pix][c]

    transpose_x_hwc_f16<<<512, 256, 0, stream>>>(x, x16h);
    transpose_dw_f16<<<9216, 256, 0, stream>>>(dw, wTh);
    transpose_ow_f16<<<1152, 256, 0, stream>>>(ow, owTh);
    offset_mfma2f<<<256, 512, 0, stream>>>(x16h, owTh, ob, off);
    deform_mfma8<<<512, 512, 0, stream>>>(x16h, wTh, off, out);
}

// Round 12
// 113.440 us; speedup vs baseline: 1.8430x; 1.8430x over previous
//
#include <hip/hip_runtime.h>
#include <hip/hip_bf16.h>

typedef __attribute__((ext_vector_type(4))) float f32x4;
typedef __attribute__((ext_vector_type(2))) _Float16 h2;
typedef __attribute__((ext_vector_type(8))) _Float16 f16x8;

// raw workgroup barrier: waits LDS ops only (no vmcnt drain -> global prefetch
// stays in flight across the barrier; __syncthreads would drain vmcnt(0))
#define LGKM_BARRIER() asm volatile("s_waitcnt lgkmcnt(0)\n\ts_barrier" ::: "memory")

// ---------------- x [2][256][4096] f32 -> x16h [2][4096][256] f16 (HWC) ----------------
__global__ __launch_bounds__(256) void transpose_x_hwc_f16(const float* __restrict__ x,
                                                           unsigned short* __restrict__ x16h) {
    __shared__ float s[64][65];
    int blk = blockIdx.x;                 // 2 b * 4 ct * 64 pt = 512
    int b = blk >> 8, ct = (blk >> 6) & 3, pt = blk & 63;
    int c0 = ct * 64, p0 = pt * 64;
    int tid = threadIdx.x;
    int tr = tid >> 6, tc = tid & 63;
#pragma unroll
    for (int i = 0; i < 16; ++i) {
        int c = i * 4 + tr;
        s[c][tc] = x[((size_t)b * 256 + c0 + c) * 4096 + p0 + tc];
    }
    __syncthreads();
#pragma unroll
    for (int i = 0; i < 16; ++i) {
        int pp = i * 4 + tr;
        _Float16 h = (_Float16)s[tc][pp];
        x16h[((size_t)b * 4096 + p0 + pp) * 256 + c0 + tc] = *(unsigned short*)&h;
    }
}

// dweights [4][256][256][3][3] fp32 -> wTh [i][k][o][c] f16
__global__ __launch_bounds__(256) void transpose_dw_f16(const float* __restrict__ dw,
                                                        unsigned short* __restrict__ wTh) {
    int idx = blockIdx.x * 256 + threadIdx.x;      // 2359296
    int c = idx & 255;
    int o = (idx >> 8) & 255;
    int rest = idx >> 16;
    int k = rest % 9, i = rest / 9;
    _Float16 h = (_Float16)dw[(((i << 8) + o) * 256 + c) * 9 + k];
    wTh[idx] = *(unsigned short*)&h;
}

// oweights [4][18][256][3][3] fp32 -> owTh [r][k][32][256] f16 (rows 18..31 zero)
__global__ __launch_bounds__(256) void transpose_ow_f16(const float* __restrict__ ow,
                                                        unsigned short* __restrict__ owTh) {
    int idx = blockIdx.x * 256 + threadIdx.x;      // 294912
    int c = idx & 255;
    int m = (idx >> 8) & 31;
    int rk = idx >> 13;
    int k = rk % 9, r = rk / 9;
    float v = (m < 18) ? ow[((r * 18 + m) * 256 + c) * 9 + k] : 0.f;
    _Float16 h = (_Float16)v;
    owTh[idx] = *(unsigned short*)&h;
}

// ---------------- offset conv: f16 HWC dense staging + prefetch + raw barriers ----------------
__global__ __launch_bounds__(512) void offset_mfma2f(const unsigned short* __restrict__ x16h,
                                                     const unsigned short* __restrict__ owTh,
                                                     const float* __restrict__ obias,
                                                     float* __restrict__ off) {
    __shared__ short    s_a[4][32][8];
    __shared__ short    s_b[4][128][8];
    __shared__ int      s_pix[9][128];
    __shared__ unsigned s_msk[9][128];

    const int blk = blockIdx.x;
    const int r = (blk & 7) >> 1, b = blk & 1;
    const int px0 = (blk >> 3) << 7;
    const int rate = 6 * (r + 1);

    const int tid = threadIdx.x;
    const int lane = tid & 63;
    const int w = tid >> 6;
    const int kg = lane >> 4, lm = lane & 15;
    const int sg = tid >> 7, spx = tid & 127;
    const int mA = (tid & 127) >> 2, kgA = tid & 3;

    const unsigned short* xbh = x16h + (size_t)b * 1048576;
    const unsigned short* wrb = owTh + (size_t)r * 9 * 32 * 256;

    for (int e = tid; e < 1152; e += 512) {
        int k = e >> 7, pl = e & 127;
        int pg = px0 + pl;
        int yy = (pg >> 6) + (k / 3 - 1) * rate;
        int xx = (pg & 63) + (k % 3 - 1) * rate;
        bool v = ((unsigned)yy < 64u) && ((unsigned)xx < 64u);
        int cy = min(max(yy, 0), 63), cx = min(max(xx, 0), 63);
        s_pix[k][pl] = cy * 64 + cx;
        s_msk[k][pl] = v ? 0xFFFFFFFFu : 0u;
    }
    __syncthreads();

    f32x4 acc0 = (f32x4)(0.f), acc1 = (f32x4)(0.f);

    uint4 a, v;
    if (tid < 128) a = *(const uint4*)(wrb + (size_t)mA * 256 + kgA * 8);
    {
        int pix = s_pix[0][spx];
        v = *(const uint4*)(xbh + (size_t)pix * 256 + sg * 8);
    }
    unsigned m = s_msk[0][spx];

    for (int t = 0; t < 72; ++t) {
        uint4 pk = make_uint4(v.x & m, v.y & m, v.z & m, v.w & m);

        LGKM_BARRIER();                 // reads of prev step done (LDS only)
        if (tid < 128) *(uint4*)&s_a[kgA][mA][0] = a;
        *(uint4*)&s_b[sg][spx][0] = pk;
        LGKM_BARRIER();                 // staging visible (LDS only)

        if (t < 71) {
            int tn = t + 1, tapn = tn >> 3, c0n = (tn & 7) << 5;
            if (tid < 128)
                a = *(const uint4*)(wrb + ((size_t)tapn * 32 + mA) * 256 + c0n + kgA * 8);
            int pix = s_pix[tapn][spx];
            m = s_msk[tapn][spx];
            v = *(const uint4*)(xbh + (size_t)pix * 256 + c0n + sg * 8);
        }

        f16x8 bf  = *(const f16x8*)&s_b[kg][w * 16 + lm][0];
        f16x8 af0 = *(const f16x8*)&s_a[kg][lm][0];
        f16x8 af1 = *(const f16x8*)&s_a[kg][16 + lm][0];
        acc0 = __builtin_amdgcn_mfma_f32_16x16x32_f16(af0, bf, acc0, 0, 0, 0);
        acc1 = __builtin_amdgcn_mfma_f32_16x16x32_f16(af1, bf, acc1, 0, 0, 0);
    }

    const float* bias = obias + r * 18;
    float* ob = off + (size_t)(r * 2 + b) * 18 * 4096;
    int px = px0 + w * 16 + lm;
#pragma unroll
    for (int reg = 0; reg < 4; ++reg) {
        int mm = kg * 4 + reg;
        ob[(size_t)mm * 4096 + px] = fmaxf(acc0[reg] + bias[mm], 0.f);
        int m1 = 16 + mm;
        if (m1 < 18)
            ob[(size_t)m1 * 4096 + px] = fmaxf(acc1[reg] + bias[m1], 0.f);
    }
}

// ---------------- deformable conv v9: r10 structure + raw lgkm barriers ----------------
// grid: 512 blocks; blk&7 = (i,b), blk>>3 = 64-px tile. 512 threads = 8 waves.
// Single change vs r10 (67.5us verified): __syncthreads -> lgkm-only barrier, so the
// A/v prefetch issued post-barrier2 stays in flight across barrier1 of the next step
// (syncthreads' vmcnt(0) drain was re-exposing gather latency every step).
__global__ __launch_bounds__(512, 2) void deform_mfma9(const unsigned short* __restrict__ x16h,
                                                       const unsigned short* __restrict__ wTh,
                                                       const float* __restrict__ off,
                                                       float* __restrict__ out) {
    __shared__ short  s_a[256][64];     // [o][64 step-ch], col ^= (o&7)*8 swizzle  32 KB
    __shared__ short  s_b[64][64];      // [px][oct^(px&7) octets of 8ch]            8 KB
    __shared__ int4   s_pix[9][64];
    __shared__ float4 s_wt[9][64];

    const int blk = blockIdx.x;
    const int i = (blk & 7) >> 1, b = blk & 1;
    const int px0 = (blk >> 3) << 6;
    const int r = (i + 3) & 3;
    const int rate = 6 * (i + 1);

    const int tid = threadIdx.x;
    const int lane = tid & 63;
    const int w = tid >> 6;
    const int wo = w >> 1, wp = w & 1;
    const int kg = lane >> 4, lm = lane & 15;
    const int pxS = tid >> 3, chgS = tid & 7;
    const int oA = tid >> 3, partA = tid & 7;
    const int colA = (partA * 8) ^ ((oA & 7) * 8);

    const unsigned short* xbh = x16h + (size_t)b * 1048576;
    const float* offb = off + (size_t)(r * 2 + b) * 18 * 4096;
    const unsigned short* wib = wTh + (size_t)i * 9 * 65536;

    for (int e = tid; e < 576; e += 512) {
        int k = e >> 6, pl = e & 63;
        int pg = px0 + pl;
        int yy = pg >> 6, xc = pg & 63;
        float dy = offb[(size_t)(2 * k) * 4096 + pg];
        float dx = offb[(size_t)(2 * k + 1) * 4096 + pg];
        float py = (float)(yy + (k / 3 - 1) * rate) + dy;
        float pxf = (float)(xc + (k % 3 - 1) * rate) + dx;
        float fy = floorf(py), fx = floorf(pxf);
        int y0 = (int)fy, x0 = (int)fx;
        float wy = py - fy, wx = pxf - fx;
        float vy0 = ((unsigned)y0 < 64u) ? 1.f : 0.f;
        float vy1 = ((unsigned)(y0 + 1) < 64u) ? 1.f : 0.f;
        float vx0 = ((unsigned)x0 < 64u) ? 1.f : 0.f;
        float vx1 = ((unsigned)(x0 + 1) < 64u) ? 1.f : 0.f;
        int cy0 = min(max(y0, 0), 63), cy1 = min(max(y0 + 1, 0), 63);
        int cx0 = min(max(x0, 0), 63), cx1 = min(max(x0 + 1, 0), 63);
        s_pix[k][pl] = make_int4(cy0 * 64 + cx0, cy0 * 64 + cx1,
                                 cy1 * 64 + cx0, cy1 * 64 + cx1);
        s_wt[k][pl] = make_float4(vy0 * vx0 * (1.f - wy) * (1.f - wx),
                                  vy0 * vx1 * (1.f - wy) * wx,
                                  vy1 * vx0 * wy * (1.f - wx),
                                  vy1 * vx1 * wy * wx);
    }
    __syncthreads();

    f32x4 acc[4][2];
#pragma unroll
    for (int mi = 0; mi < 4; ++mi) {
        acc[mi][0] = (f32x4)(0.f);
        acc[mi][1] = (f32x4)(0.f);
    }

    // prologue: issue loads for t=0
    uint4 a0, a1, a2, a3, v0, v1, v2, v3;
    {
        const unsigned short* wrow = wib + partA * 8;
        a0 = *(const uint4*)(wrow + (size_t)(oA      ) * 256);
        a1 = *(const uint4*)(wrow + (size_t)(oA +  64) * 256);
        a2 = *(const uint4*)(wrow + (size_t)(oA + 128) * 256);
        a3 = *(const uint4*)(wrow + (size_t)(oA + 192) * 256);
        int4 p = s_pix[0][pxS];
        const unsigned short* xch = xbh + chgS * 8;
        v0 = *(const uint4*)(xch + ((size_t)p.x << 8));
        v1 = *(const uint4*)(xch + ((size_t)p.y << 8));
        v2 = *(const uint4*)(xch + ((size_t)p.z << 8));
        v3 = *(const uint4*)(xch + ((size_t)p.w << 8));
    }

    for (int t = 0; t < 36; ++t) {
        const int tap = t >> 2;

        // lerp current step's corners (packed f16)
        uint4 pk;
        {
            float4 qwf = s_wt[tap][pxS];
            h2 qx = (h2)((_Float16)qwf.x), qy = (h2)((_Float16)qwf.y);
            h2 qz = (h2)((_Float16)qwf.z), qv = (h2)((_Float16)qwf.w);
            h2 r0 = (*(h2*)&v0.x) * qx + (*(h2*)&v1.x) * qy + (*(h2*)&v2.x) * qz + (*(h2*)&v3.x) * qv;
            h2 r1 = (*(h2*)&v0.y) * qx + (*(h2*)&v1.y) * qy + (*(h2*)&v2.y) * qz + (*(h2*)&v3.y) * qv;
            h2 r2 = (*(h2*)&v0.z) * qx + (*(h2*)&v1.z) * qy + (*(h2*)&v2.z) * qz + (*(h2*)&v3.z) * qv;
            h2 r3 = (*(h2*)&v0.w) * qx + (*(h2*)&v1.w) * qy + (*(h2*)&v2.w) * qz + (*(h2*)&v3.w) * qv;
            pk = make_uint4(*(unsigned*)&r0, *(unsigned*)&r1, *(unsigned*)&r2, *(unsigned*)&r3);
        }

        LGKM_BARRIER();                 // prev step's LDS reads done (no vmcnt drain)
        *(uint4*)&s_a[oA      ][colA] = a0;
        *(uint4*)&s_a[oA +  64][colA] = a1;
        *(uint4*)&s_a[oA + 128][colA] = a2;
        *(uint4*)&s_a[oA + 192][colA] = a3;
        *(uint4*)&s_b[pxS][(chgS ^ (pxS & 7)) * 8] = pk;
        LGKM_BARRIER();                 // staging visible (no vmcnt drain)

        if (t < 35) {   // prefetch t+1: flies across next step's barriers now
            int tn = t + 1, tapn = tn >> 2, c0n = (tn & 3) << 6;
            const unsigned short* wrow = wib + (size_t)tapn * 65536 + c0n + partA * 8;
            a0 = *(const uint4*)(wrow + (size_t)(oA      ) * 256);
            a1 = *(const uint4*)(wrow + (size_t)(oA +  64) * 256);
            a2 = *(const uint4*)(wrow + (size_t)(oA + 128) * 256);
            a3 = *(const uint4*)(wrow + (size_t)(oA + 192) * 256);
            int4 p = s_pix[tapn][pxS];
            const unsigned short* xch = xbh + c0n + chgS * 8;
            v0 = *(const uint4*)(xch + ((size_t)p.x << 8));
            v1 = *(const uint4*)(xch + ((size_t)p.y << 8));
            v2 = *(const uint4*)(xch + ((size_t)p.z << 8));
            v3 = *(const uint4*)(xch + ((size_t)p.w << 8));
        }

#pragma unroll
        for (int kf = 0; kf < 2; ++kf) {
            int oct = kf * 4 + kg;
            int bcol = (oct ^ (lm & 7)) * 8;
            f16x8 bf0 = *(const f16x8*)&s_b[wp * 32 + lm][bcol];
            f16x8 bf1 = *(const f16x8*)&s_b[wp * 32 + 16 + lm][bcol];
#pragma unroll
            for (int mi = 0; mi < 4; ++mi) {
                int o = wo * 64 + mi * 16 + lm;
                int col = (oct * 8) ^ ((o & 7) * 8);
                f16x8 af = *(const f16x8*)&s_a[o][col];
                acc[mi][0] = __builtin_amdgcn_mfma_f32_16x16x32_f16(af, bf0, acc[mi][0], 0, 0, 0);
                acc[mi][1] = __builtin_amdgcn_mfma_f32_16x16x32_f16(af, bf1, acc[mi][1], 0, 0, 0);
            }
        }
    }

    // epilogue: C/D col = lane&15 (px), row = kg*4 + reg (o)
    float* ob = out + ((size_t)b * 1024 + i * 256) * 4096;
#pragma unroll
    for (int mi = 0; mi < 4; ++mi) {
        int o = wo * 64 + mi * 16 + kg * 4;
#pragma unroll
        for (int ni = 0; ni < 2; ++ni) {
            int pg = px0 + wp * 32 + ni * 16 + lm;
#pragma unroll
            for (int reg = 0; reg < 4; ++reg)
                ob[(size_t)(o + reg) * 4096 + pg] = acc[mi][ni][reg];
        }
    }
}

extern "C" void kernel_launch(void* const* d_in, const int* in_sizes, int n_in,
                              void* d_out, int out_size, void* d_ws, size_t ws_size,
                              hipStream_t stream) {
    const float* x  = (const float*)d_in[0];   // [2,256,64,64]
    const float* dw = (const float*)d_in[1];   // [4,256,256,3,3]
    const float* ow = (const float*)d_in[2];   // [4,18,256,3,3]
    const float* ob = (const float*)d_in[3];   // [4,18]
    float* out = (float*)d_out;                // [2,1024,64,64]

    float* ws  = (float*)d_ws;
    float* off = ws;                                        // 589824 f32
    unsigned short* wTh  = (unsigned short*)(ws + 589824);  // 2359296 f16
    unsigned short* owTh = wTh + 2359296;                   // 294912 f16
    unsigned short* x16h = (unsigned short*)(ws + 1916928); // 2097152 f16 [b][pix][c]

    transpose_x_hwc_f16<<<512, 256, 0, stream>>>(x, x16h);
    transpose_dw_f16<<<9216, 256, 0, stream>>>(dw, wTh);
    transpose_ow_f16<<<1152, 256, 0, stream>>>(ow, owTh);
    offset_mfma2f<<<256, 512, 0, stream>>>(x16h, owTh, ob, off);
    deform_mfma9<<<512, 512, 0, stream>>>(x16h, wTh, off, out);
}

// Round 13
// 110.641 us; speedup vs baseline: 1.8896x; 1.0253x over previous
//
#include <hip/hip_runtime.h>
#include <hip/hip_bf16.h>

typedef __attribute__((ext_vector_type(4))) float f32x4;
typedef __attribute__((ext_vector_type(2))) _Float16 h2;
typedef __attribute__((ext_vector_type(8))) _Float16 f16x8;

// raw workgroup barrier: waits LDS ops only (no vmcnt drain -> global prefetch
// stays in flight across the barrier)
#define LGKM_BARRIER() asm volatile("s_waitcnt lgkmcnt(0)\n\ts_barrier" ::: "memory")

// ---------------- x [2][256][4096] f32 -> x16h [2][4096][256] f16 (HWC) ----------------
__global__ __launch_bounds__(256) void transpose_x_hwc_f16(const float* __restrict__ x,
                                                           unsigned short* __restrict__ x16h) {
    __shared__ float s[64][65];
    int blk = blockIdx.x;                 // 2 b * 4 ct * 64 pt = 512
    int b = blk >> 8, ct = (blk >> 6) & 3, pt = blk & 63;
    int c0 = ct * 64, p0 = pt * 64;
    int tid = threadIdx.x;
    int tr = tid >> 6, tc = tid & 63;
#pragma unroll
    for (int i = 0; i < 16; ++i) {
        int c = i * 4 + tr;
        s[c][tc] = x[((size_t)b * 256 + c0 + c) * 4096 + p0 + tc];
    }
    __syncthreads();
#pragma unroll
    for (int i = 0; i < 16; ++i) {
        int pp = i * 4 + tr;
        _Float16 h = (_Float16)s[tc][pp];
        x16h[((size_t)b * 4096 + p0 + pp) * 256 + c0 + tc] = *(unsigned short*)&h;
    }
}

// dweights [4][256][256][3][3] fp32 -> wTh [i][k][o][c] f16
__global__ __launch_bounds__(256) void transpose_dw_f16(const float* __restrict__ dw,
                                                        unsigned short* __restrict__ wTh) {
    int idx = blockIdx.x * 256 + threadIdx.x;      // 2359296
    int c = idx & 255;
    int o = (idx >> 8) & 255;
    int rest = idx >> 16;
    int k = rest % 9, i = rest / 9;
    _Float16 h = (_Float16)dw[(((i << 8) + o) * 256 + c) * 9 + k];
    wTh[idx] = *(unsigned short*)&h;
}

// oweights [4][18][256][3][3] fp32 -> owTh [r][k][32][256] f16 (rows 18..31 zero)
__global__ __launch_bounds__(256) void transpose_ow_f16(const float* __restrict__ ow,
                                                        unsigned short* __restrict__ owTh) {
    int idx = blockIdx.x * 256 + threadIdx.x;      // 294912
    int c = idx & 255;
    int m = (idx >> 8) & 31;
    int rk = idx >> 13;
    int k = rk % 9, r = rk / 9;
    float v = (m < 18) ? ow[((r * 18 + m) * 256 + c) * 9 + k] : 0.f;
    _Float16 h = (_Float16)v;
    owTh[idx] = *(unsigned short*)&h;
}

// ---------------- offset conv: f16 HWC dense staging + prefetch + raw barriers (r12) ----------------
__global__ __launch_bounds__(512) void offset_mfma2f(const unsigned short* __restrict__ x16h,
                                                     const unsigned short* __restrict__ owTh,
                                                     const float* __restrict__ obias,
                                                     float* __restrict__ off) {
    __shared__ short    s_a[4][32][8];
    __shared__ short    s_b[4][128][8];
    __shared__ int      s_pix[9][128];
    __shared__ unsigned s_msk[9][128];

    const int blk = blockIdx.x;
    const int r = (blk & 7) >> 1, b = blk & 1;
    const int px0 = (blk >> 3) << 7;
    const int rate = 6 * (r + 1);

    const int tid = threadIdx.x;
    const int lane = tid & 63;
    const int w = tid >> 6;
    const int kg = lane >> 4, lm = lane & 15;
    const int sg = tid >> 7, spx = tid & 127;
    const int mA = (tid & 127) >> 2, kgA = tid & 3;

    const unsigned short* xbh = x16h + (size_t)b * 1048576;
    const unsigned short* wrb = owTh + (size_t)r * 9 * 32 * 256;

    for (int e = tid; e < 1152; e += 512) {
        int k = e >> 7, pl = e & 127;
        int pg = px0 + pl;
        int yy = (pg >> 6) + (k / 3 - 1) * rate;
        int xx = (pg & 63) + (k % 3 - 1) * rate;
        bool v = ((unsigned)yy < 64u) && ((unsigned)xx < 64u);
        int cy = min(max(yy, 0), 63), cx = min(max(xx, 0), 63);
        s_pix[k][pl] = cy * 64 + cx;
        s_msk[k][pl] = v ? 0xFFFFFFFFu : 0u;
    }
    __syncthreads();

    f32x4 acc0 = (f32x4)(0.f), acc1 = (f32x4)(0.f);

    uint4 a, v;
    if (tid < 128) a = *(const uint4*)(wrb + (size_t)mA * 256 + kgA * 8);
    {
        int pix = s_pix[0][spx];
        v = *(const uint4*)(xbh + (size_t)pix * 256 + sg * 8);
    }
    unsigned m = s_msk[0][spx];

    for (int t = 0; t < 72; ++t) {
        uint4 pk = make_uint4(v.x & m, v.y & m, v.z & m, v.w & m);

        LGKM_BARRIER();
        if (tid < 128) *(uint4*)&s_a[kgA][mA][0] = a;
        *(uint4*)&s_b[sg][spx][0] = pk;
        LGKM_BARRIER();

        if (t < 71) {
            int tn = t + 1, tapn = tn >> 3, c0n = (tn & 7) << 5;
            if (tid < 128)
                a = *(const uint4*)(wrb + ((size_t)tapn * 32 + mA) * 256 + c0n + kgA * 8);
            int pix = s_pix[tapn][spx];
            m = s_msk[tapn][spx];
            v = *(const uint4*)(xbh + (size_t)pix * 256 + c0n + sg * 8);
        }

        f16x8 bf  = *(const f16x8*)&s_b[kg][w * 16 + lm][0];
        f16x8 af0 = *(const f16x8*)&s_a[kg][lm][0];
        f16x8 af1 = *(const f16x8*)&s_a[kg][16 + lm][0];
        acc0 = __builtin_amdgcn_mfma_f32_16x16x32_f16(af0, bf, acc0, 0, 0, 0);
        acc1 = __builtin_amdgcn_mfma_f32_16x16x32_f16(af1, bf, acc1, 0, 0, 0);
    }

    const float* bias = obias + r * 18;
    float* ob = off + (size_t)(r * 2 + b) * 18 * 4096;
    int px = px0 + w * 16 + lm;
#pragma unroll
    for (int reg = 0; reg < 4; ++reg) {
        int mm = kg * 4 + reg;
        ob[(size_t)mm * 4096 + px] = fmaxf(acc0[reg] + bias[mm], 0.f);
        int m1 = 16 + mm;
        if (m1 < 18)
            ob[(size_t)m1 * 4096 + px] = fmaxf(acc1[reg] + bias[m1], 0.f);
    }
}

// ---------------- deformable conv v10: 256 blocks, 256o x 128px tile, wave 64o x 64px ----------------
// grid: 256 blocks = 1/CU; blk&7 = (i,b) [XCD-aligned], blk>>3 = 128-px tile (0..31).
// 8 waves = 4 wo x 2 wp. K-step 64, 36 steps, 2 raw barriers/step.
// r12 lesson: LDS-BW-bound (136KB/block-step, 2 blocks sharing CU). This tile:
// 176KB per 2x FLOPs = 21 vs 32.4 B/KFLOP, and 1 block/CU owns full LDS BW.
__global__ __launch_bounds__(512, 2) void deform_mfma10(const unsigned short* __restrict__ x16h,
                                                        const unsigned short* __restrict__ wTh,
                                                        const float* __restrict__ off,
                                                        float* __restrict__ out) {
    __shared__ short  s_a[256][64];     // [o][64 step-ch], col ^= (o&7)*8 swizzle  32 KB
    __shared__ short  s_b[128][64];     // [px][oct^(px&7) octets of 8ch]           16 KB
    __shared__ int4   s_pix[9][128];    // 18 KB
    __shared__ float4 s_wt[9][128];     // 18 KB

    const int blk = blockIdx.x;
    const int i = (blk & 7) >> 1, b = blk & 1;
    const int px0 = (blk >> 3) << 7;
    const int r = (i + 3) & 3;
    const int rate = 6 * (i + 1);

    const int tid = threadIdx.x;
    const int lane = tid & 63;
    const int w = tid >> 6;
    const int wo = w >> 1, wp = w & 1;          // o-quarter (64 rows), px-half (64 px)
    const int kg = lane >> 4, lm = lane & 15;
    const int pxS = tid >> 2, chgS = tid & 3;   // B staging: pixel (0..127), octet base (0..3)
    const int oA = tid >> 3, partA = tid & 7;   // A staging: o-row, 16B part
    const int colA = (partA * 8) ^ ((oA & 7) * 8);

    const unsigned short* xbh = x16h + (size_t)b * 1048576;   // [pix][256ch] f16
    const float* offb = off + (size_t)(r * 2 + b) * 18 * 4096;
    const unsigned short* wib = wTh + (size_t)i * 9 * 65536;

    // bilinear coords/weights: 9 taps x 128 px (validity folded into weights)
    for (int e = tid; e < 1152; e += 512) {
        int k = e >> 7, pl = e & 127;
        int pg = px0 + pl;
        int yy = pg >> 6, xc = pg & 63;
        float dy = offb[(size_t)(2 * k) * 4096 + pg];
        float dx = offb[(size_t)(2 * k + 1) * 4096 + pg];
        float py = (float)(yy + (k / 3 - 1) * rate) + dy;
        float pxf = (float)(xc + (k % 3 - 1) * rate) + dx;
        float fy = floorf(py), fx = floorf(pxf);
        int y0 = (int)fy, x0 = (int)fx;
        float wy = py - fy, wx = pxf - fx;
        float vy0 = ((unsigned)y0 < 64u) ? 1.f : 0.f;
        float vy1 = ((unsigned)(y0 + 1) < 64u) ? 1.f : 0.f;
        float vx0 = ((unsigned)x0 < 64u) ? 1.f : 0.f;
        float vx1 = ((unsigned)(x0 + 1) < 64u) ? 1.f : 0.f;
        int cy0 = min(max(y0, 0), 63), cy1 = min(max(y0 + 1, 0), 63);
        int cx0 = min(max(x0, 0), 63), cx1 = min(max(x0 + 1, 0), 63);
        s_pix[k][pl] = make_int4(cy0 * 64 + cx0, cy0 * 64 + cx1,
                                 cy1 * 64 + cx0, cy1 * 64 + cx1);
        s_wt[k][pl] = make_float4(vy0 * vx0 * (1.f - wy) * (1.f - wx),
                                  vy0 * vx1 * (1.f - wy) * wx,
                                  vy1 * vx0 * wy * (1.f - wx),
                                  vy1 * vx1 * wy * wx);
    }
    __syncthreads();

    f32x4 acc[4][4];
#pragma unroll
    for (int mi = 0; mi < 4; ++mi)
#pragma unroll
        for (int ni = 0; ni < 4; ++ni) acc[mi][ni] = (f32x4)(0.f);

    // prologue: issue loads for t=0
    uint4 a0, a1, a2, a3;                   // A: 4 coalesced 16B parts
    uint4 u0, u1, u2, u3, w0, w1, w2, w3;   // B corners: region0 (oct chgS), region1 (oct chgS+4)
    {
        const unsigned short* wrow = wib + partA * 8;
        a0 = *(const uint4*)(wrow + (size_t)(oA      ) * 256);
        a1 = *(const uint4*)(wrow + (size_t)(oA +  64) * 256);
        a2 = *(const uint4*)(wrow + (size_t)(oA + 128) * 256);
        a3 = *(const uint4*)(wrow + (size_t)(oA + 192) * 256);
        int4 p = s_pix[0][pxS];
        const unsigned short* xch = xbh + chgS * 8;
        u0 = *(const uint4*)(xch + ((size_t)p.x << 8));
        u1 = *(const uint4*)(xch + ((size_t)p.y << 8));
        u2 = *(const uint4*)(xch + ((size_t)p.z << 8));
        u3 = *(const uint4*)(xch + ((size_t)p.w << 8));
        w0 = *(const uint4*)(xch + ((size_t)p.x << 8) + 32);
        w1 = *(const uint4*)(xch + ((size_t)p.y << 8) + 32);
        w2 = *(const uint4*)(xch + ((size_t)p.z << 8) + 32);
        w3 = *(const uint4*)(xch + ((size_t)p.w << 8) + 32);
    }

    for (int t = 0; t < 36; ++t) {
        const int tap = t >> 2;

        // lerp both octet-regions (packed f16)
        uint4 pkA, pkB;
        {
            float4 qwf = s_wt[tap][pxS];
            h2 qx = (h2)((_Float16)qwf.x), qy = (h2)((_Float16)qwf.y);
            h2 qz = (h2)((_Float16)qwf.z), qv = (h2)((_Float16)qwf.w);
            h2 r0 = (*(h2*)&u0.x) * qx + (*(h2*)&u1.x) * qy + (*(h2*)&u2.x) * qz + (*(h2*)&u3.x) * qv;
            h2 r1 = (*(h2*)&u0.y) * qx + (*(h2*)&u1.y) * qy + (*(h2*)&u2.y) * qz + (*(h2*)&u3.y) * qv;
            h2 r2 = (*(h2*)&u0.z) * qx + (*(h2*)&u1.z) * qy + (*(h2*)&u2.z) * qz + (*(h2*)&u3.z) * qv;
            h2 r3 = (*(h2*)&u0.w) * qx + (*(h2*)&u1.w) * qy + (*(h2*)&u2.w) * qz + (*(h2*)&u3.w) * qv;
            pkA = make_uint4(*(unsigned*)&r0, *(unsigned*)&r1, *(unsigned*)&r2, *(unsigned*)&r3);
            h2 s0 = (*(h2*)&w0.x) * qx + (*(h2*)&w1.x) * qy + (*(h2*)&w2.x) * qz + (*(h2*)&w3.x) * qv;
            h2 s1 = (*(h2*)&w0.y) * qx + (*(h2*)&w1.y) * qy + (*(h2*)&w2.y) * qz + (*(h2*)&w3.y) * qv;
            h2 s2 = (*(h2*)&w0.z) * qx + (*(h2*)&w1.z) * qy + (*(h2*)&w2.z) * qz + (*(h2*)&w3.z) * qv;
            h2 s3 = (*(h2*)&w0.w) * qx + (*(h2*)&w1.w) * qy + (*(h2*)&w2.w) * qz + (*(h2*)&w3.w) * qv;
            pkB = make_uint4(*(unsigned*)&s0, *(unsigned*)&s1, *(unsigned*)&s2, *(unsigned*)&s3);
        }

        LGKM_BARRIER();                 // prev step's LDS reads done
        *(uint4*)&s_a[oA      ][colA] = a0;
        *(uint4*)&s_a[oA +  64][colA] = a1;
        *(uint4*)&s_a[oA + 128][colA] = a2;
        *(uint4*)&s_a[oA + 192][colA] = a3;
        *(uint4*)&s_b[pxS][(chgS ^ (pxS & 7)) * 8]       = pkA;
        *(uint4*)&s_b[pxS][((chgS + 4) ^ (pxS & 7)) * 8] = pkB;
        LGKM_BARRIER();                 // staging visible

        if (t < 35) {                   // prefetch t+1: flies through MFMA phase + barriers
            int tn = t + 1, tapn = tn >> 2, c0n = (tn & 3) << 6;
            const unsigned short* wrow = wib + (size_t)tapn * 65536 + c0n + partA * 8;
            a0 = *(const uint4*)(wrow + (size_t)(oA      ) * 256);
            a1 = *(const uint4*)(wrow + (size_t)(oA +  64) * 256);
            a2 = *(const uint4*)(wrow + (size_t)(oA + 128) * 256);
            a3 = *(const uint4*)(wrow + (size_t)(oA + 192) * 256);
            int4 p = s_pix[tapn][pxS];
            const unsigned short* xch = xbh + c0n + chgS * 8;
            u0 = *(const uint4*)(xch + ((size_t)p.x << 8));
            u1 = *(const uint4*)(xch + ((size_t)p.y << 8));
            u2 = *(const uint4*)(xch + ((size_t)p.z << 8));
            u3 = *(const uint4*)(xch + ((size_t)p.w << 8));
            w0 = *(const uint4*)(xch + ((size_t)p.x << 8) + 32);
            w1 = *(const uint4*)(xch + ((size_t)p.y << 8) + 32);
            w2 = *(const uint4*)(xch + ((size_t)p.z << 8) + 32);
            w3 = *(const uint4*)(xch + ((size_t)p.w << 8) + 32);
        }

        // MFMA phase: wave = 64o x 64px; A col == B col == (oct^(lm&7))*8
#pragma unroll
        for (int kf = 0; kf < 2; ++kf) {
            int oct = kf * 4 + kg;
            int col = (oct ^ (lm & 7)) * 8;
            f16x8 bf0 = *(const f16x8*)&s_b[wp * 64 + lm][col];
            f16x8 bf1 = *(const f16x8*)&s_b[wp * 64 + 16 + lm][col];
            f16x8 bf2 = *(const f16x8*)&s_b[wp * 64 + 32 + lm][col];
            f16x8 bf3 = *(const f16x8*)&s_b[wp * 64 + 48 + lm][col];
#pragma unroll
            for (int mi = 0; mi < 4; ++mi) {
                f16x8 af = *(const f16x8*)&s_a[wo * 64 + mi * 16 + lm][col];
                acc[mi][0] = __builtin_amdgcn_mfma_f32_16x16x32_f16(af, bf0, acc[mi][0], 0, 0, 0);
                acc[mi][1] = __builtin_amdgcn_mfma_f32_16x16x32_f16(af, bf1, acc[mi][1], 0, 0, 0);
                acc[mi][2] = __builtin_amdgcn_mfma_f32_16x16x32_f16(af, bf2, acc[mi][2], 0, 0, 0);
                acc[mi][3] = __builtin_amdgcn_mfma_f32_16x16x32_f16(af, bf3, acc[mi][3], 0, 0, 0);
            }
        }
    }

    // epilogue: C/D col = lane&15 (px), row = kg*4 + reg (o)
    float* ob = out + ((size_t)b * 1024 + i * 256) * 4096;
#pragma unroll
    for (int mi = 0; mi < 4; ++mi) {
        int o = wo * 64 + mi * 16 + kg * 4;
#pragma unroll
        for (int ni = 0; ni < 4; ++ni) {
            int pg = px0 + wp * 64 + ni * 16 + lm;
#pragma unroll
            for (int reg = 0; reg < 4; ++reg)
                ob[(size_t)(o + reg) * 4096 + pg] = acc[mi][ni][reg];
        }
    }
}

extern "C" void kernel_launch(void* const* d_in, const int* in_sizes, int n_in,
                              void* d_out, int out_size, void* d_ws, size_t ws_size,
                              hipStream_t stream) {
    const float* x  = (const float*)d_in[0];   // [2,256,64,64]
    const float* dw = (const float*)d_in[1];   // [4,256,256,3,3]
    const float* ow = (const float*)d_in[2];   // [4,18,256,3,3]
    const float* ob = (const float*)d_in[3];   // [4,18]
    float* out = (float*)d_out;                // [2,1024,64,64]

    float* ws  = (float*)d_ws;
    float* off = ws;                                        // 589824 f32
    unsigned short* wTh  = (unsigned short*)(ws + 589824);  // 2359296 f16
    unsigned short* owTh = wTh + 2359296;                   // 294912 f16
    unsigned short* x16h = (unsigned short*)(ws + 1916928); // 2097152 f16 [b][pix][c]

    transpose_x_hwc_f16<<<512, 256, 0, stream>>>(x, x16h);
    transpose_dw_f16<<<9216, 256, 0, stream>>>(dw, wTh);
    transpose_ow_f16<<<1152, 256, 0, stream>>>(ow, owTh);
    offset_mfma2f<<<256, 512, 0, stream>>>(x16h, owTh, ob, off);
    deform_mfma10<<<256, 512, 0, stream>>>(x16h, wTh, off, out);
}

// Round 14
// 106.747 us; speedup vs baseline: 1.9586x; 1.0365x over previous
//
#include <hip/hip_runtime.h>
#include <hip/hip_bf16.h>

typedef __attribute__((ext_vector_type(4))) float f32x4;
typedef __attribute__((ext_vector_type(2))) _Float16 h2;
typedef __attribute__((ext_vector_type(8))) _Float16 f16x8;

// raw workgroup barrier: waits LDS ops only (no vmcnt drain -> global prefetch
// stays in flight across the barrier)
#define LGKM_BARRIER() asm volatile("s_waitcnt lgkmcnt(0)\n\ts_barrier" ::: "memory")

__device__ __forceinline__ uint4 lerp4(uint4 c0, uint4 c1, uint4 c2, uint4 c3,
                                       h2 qx, h2 qy, h2 qz, h2 qv) {
    h2 r0 = (*(h2*)&c0.x) * qx + (*(h2*)&c1.x) * qy + (*(h2*)&c2.x) * qz + (*(h2*)&c3.x) * qv;
    h2 r1 = (*(h2*)&c0.y) * qx + (*(h2*)&c1.y) * qy + (*(h2*)&c2.y) * qz + (*(h2*)&c3.y) * qv;
    h2 r2 = (*(h2*)&c0.z) * qx + (*(h2*)&c1.z) * qy + (*(h2*)&c2.z) * qz + (*(h2*)&c3.z) * qv;
    h2 r3 = (*(h2*)&c0.w) * qx + (*(h2*)&c1.w) * qy + (*(h2*)&c2.w) * qz + (*(h2*)&c3.w) * qv;
    return make_uint4(*(unsigned*)&r0, *(unsigned*)&r1, *(unsigned*)&r2, *(unsigned*)&r3);
}

// ---------------- x [2][256][4096] f32 -> x16h [2][4096][256] f16 (HWC) ----------------
__global__ __launch_bounds__(256) void transpose_x_hwc_f16(const float* __restrict__ x,
                                                           unsigned short* __restrict__ x16h) {
    __shared__ float s[64][65];
    int blk = blockIdx.x;                 // 2 b * 4 ct * 64 pt = 512
    int b = blk >> 8, ct = (blk >> 6) & 3, pt = blk & 63;
    int c0 = ct * 64, p0 = pt * 64;
    int tid = threadIdx.x;
    int tr = tid >> 6, tc = tid & 63;
#pragma unroll
    for (int i = 0; i < 16; ++i) {
        int c = i * 4 + tr;
        s[c][tc] = x[((size_t)b * 256 + c0 + c) * 4096 + p0 + tc];
    }
    __syncthreads();
#pragma unroll
    for (int i = 0; i < 16; ++i) {
        int pp = i * 4 + tr;
        _Float16 h = (_Float16)s[tc][pp];
        x16h[((size_t)b * 4096 + p0 + pp) * 256 + c0 + tc] = *(unsigned short*)&h;
    }
}

// dweights [4][256][256][3][3] fp32 -> wTh [i][k][o][c] f16  (coalesced rewrite)
// block = (i,o): coalesced float4 read -> LDS -> stride-9 LDS read (9 odd: conflict-free)
// -> 9 coalesced 2B stores.
__global__ __launch_bounds__(256) void transpose_dw_f16(const float* __restrict__ dw,
                                                        unsigned short* __restrict__ wTh) {
    __shared__ float s[2304];
    int blk = blockIdx.x;                 // 4 i * 256 o = 1024
    int i = blk >> 8, o = blk & 255;
    const float* src = dw + (size_t)(i * 256 + o) * 2304;
    int tid = threadIdx.x;
#pragma unroll
    for (int e = tid; e < 576; e += 256)
        *(float4*)&s[e * 4] = *(const float4*)&src[e * 4];
    __syncthreads();
#pragma unroll
    for (int k = 0; k < 9; ++k) {
        _Float16 h = (_Float16)s[tid * 9 + k];
        wTh[(((size_t)i * 9 + k) * 256 + o) * 256 + tid] = *(unsigned short*)&h;
    }
}

// oweights [4][18][256][3][3] fp32 -> owTh [r][k][32][256] f16 (rows 18..31 zero)
__global__ __launch_bounds__(256) void transpose_ow_f16(const float* __restrict__ ow,
                                                        unsigned short* __restrict__ owTh) {
    int idx = blockIdx.x * 256 + threadIdx.x;      // 294912
    int c = idx & 255;
    int m = (idx >> 8) & 31;
    int rk = idx >> 13;
    int k = rk % 9, r = rk / 9;
    float v = (m < 18) ? ow[((r * 18 + m) * 256 + c) * 9 + k] : 0.f;
    _Float16 h = (_Float16)v;
    owTh[idx] = *(unsigned short*)&h;
}

// ---------------- offset conv v3: K-step 64 (36 phases), prefetch, raw barriers ----------------
// grid: 256 blocks; blk&7=(r,b), blk>>3 = 128-px tile. 512 threads = 8 waves.
__global__ __launch_bounds__(512) void offset_mfma3f(const unsigned short* __restrict__ x16h,
                                                     const unsigned short* __restrict__ owTh,
                                                     const float* __restrict__ obias,
                                                     float* __restrict__ off) {
    __shared__ short    s_a[8][32][8];     // 4 KB  [octet][m][8ch]
    __shared__ short    s_b[8][128][8];    // 16 KB [octet][px][8ch]
    __shared__ int      s_pix[9][128];
    __shared__ unsigned s_msk[9][128];

    const int blk = blockIdx.x;
    const int r = (blk & 7) >> 1, b = blk & 1;
    const int px0 = (blk >> 3) << 7;
    const int rate = 6 * (r + 1);

    const int tid = threadIdx.x;
    const int lane = tid & 63;
    const int w = tid >> 6;
    const int kg = lane >> 4, lm = lane & 15;
    const int sg = tid >> 7, spx = tid & 127;        // B staging: octet base, pixel
    const int mA = (tid & 127) >> 2, kgA = tid & 3;  // A staging (tid<128)

    const unsigned short* xbh = x16h + (size_t)b * 1048576;
    const unsigned short* wrb = owTh + (size_t)r * 9 * 32 * 256;

    for (int e = tid; e < 1152; e += 512) {
        int k = e >> 7, pl = e & 127;
        int pg = px0 + pl;
        int yy = (pg >> 6) + (k / 3 - 1) * rate;
        int xx = (pg & 63) + (k % 3 - 1) * rate;
        bool v = ((unsigned)yy < 64u) && ((unsigned)xx < 64u);
        int cy = min(max(yy, 0), 63), cx = min(max(xx, 0), 63);
        s_pix[k][pl] = cy * 64 + cx;
        s_msk[k][pl] = v ? 0xFFFFFFFFu : 0u;
    }
    __syncthreads();

    f32x4 acc0 = (f32x4)(0.f), acc1 = (f32x4)(0.f);

    uint4 a_lo, a_hi, v_lo, v_hi;
    if (tid < 128) {
        a_lo = *(const uint4*)(wrb + (size_t)mA * 256 + kgA * 8);
        a_hi = *(const uint4*)(wrb + (size_t)mA * 256 + 32 + kgA * 8);
    }
    {
        int pix = s_pix[0][spx];
        v_lo = *(const uint4*)(xbh + (size_t)pix * 256 + sg * 8);
        v_hi = *(const uint4*)(xbh + (size_t)pix * 256 + 32 + sg * 8);
    }
    unsigned m = s_msk[0][spx];

    for (int t = 0; t < 36; ++t) {
        uint4 pkl = make_uint4(v_lo.x & m, v_lo.y & m, v_lo.z & m, v_lo.w & m);
        uint4 pkh = make_uint4(v_hi.x & m, v_hi.y & m, v_hi.z & m, v_hi.w & m);

        LGKM_BARRIER();
        if (tid < 128) {
            *(uint4*)&s_a[kgA][mA][0]     = a_lo;
            *(uint4*)&s_a[kgA + 4][mA][0] = a_hi;
        }
        *(uint4*)&s_b[sg][spx][0]     = pkl;
        *(uint4*)&s_b[sg + 4][spx][0] = pkh;
        LGKM_BARRIER();

        if (t < 35) {
            int tn = t + 1, tapn = tn >> 2, c0n = (tn & 3) << 6;
            if (tid < 128) {
                a_lo = *(const uint4*)(wrb + ((size_t)tapn * 32 + mA) * 256 + c0n + kgA * 8);
                a_hi = *(const uint4*)(wrb + ((size_t)tapn * 32 + mA) * 256 + c0n + 32 + kgA * 8);
            }
            int pix = s_pix[tapn][spx];
            m = s_msk[tapn][spx];
            v_lo = *(const uint4*)(xbh + (size_t)pix * 256 + c0n + sg * 8);
            v_hi = *(const uint4*)(xbh + (size_t)pix * 256 + c0n + 32 + sg * 8);
        }

#pragma unroll
        for (int kf = 0; kf < 2; ++kf) {
            int oct = kf * 4 + kg;
            f16x8 bf  = *(const f16x8*)&s_b[oct][w * 16 + lm][0];
            f16x8 af0 = *(const f16x8*)&s_a[oct][lm][0];
            f16x8 af1 = *(const f16x8*)&s_a[oct][16 + lm][0];
            acc0 = __builtin_amdgcn_mfma_f32_16x16x32_f16(af0, bf, acc0, 0, 0, 0);
            acc1 = __builtin_amdgcn_mfma_f32_16x16x32_f16(af1, bf, acc1, 0, 0, 0);
        }
    }

    const float* bias = obias + r * 18;
    float* ob = off + (size_t)(r * 2 + b) * 18 * 4096;
    int px = px0 + w * 16 + lm;
#pragma unroll
    for (int reg = 0; reg < 4; ++reg) {
        int mm = kg * 4 + reg;
        ob[(size_t)mm * 4096 + px] = fmaxf(acc0[reg] + bias[mm], 0.f);
        int m1 = 16 + mm;
        if (m1 < 18)
            ob[(size_t)m1 * 4096 + px] = fmaxf(acc1[reg] + bias[m1], 0.f);
    }
}

// ---------------- deformable conv v11: merged phases (K=128/phase, 18 phases) ----------------
// grid: 256 blocks; blk&7 = (i,b) [XCD-aligned], blk>>3 = 128-px tile.
// 8 waves = 4 wo x 2 wp, wave = 64o x 64px. Phase = 2 K-sub-steps; the 2x-long MFMA
// phase (~640cy/SIMD) now covers the corner-gather latency of the next phase's loads.
__global__ __launch_bounds__(512, 2) void deform_mfma11(const unsigned short* __restrict__ x16h,
                                                        const unsigned short* __restrict__ wTh,
                                                        const float* __restrict__ off,
                                                        float* __restrict__ out) {
    __shared__ short  s_a[256][128];    // 64 KB [o][sub*64 + (part^(o&7))*8]
    __shared__ short  s_b[128][128];    // 32 KB [px][sub*64 + (oct^(px&7))*8]
    __shared__ int4   s_pix[9][128];    // 18 KB
    __shared__ float4 s_wt[9][128];     // 18 KB

    const int blk = blockIdx.x;
    const int i = (blk & 7) >> 1, b = blk & 1;
    const int px0 = (blk >> 3) << 7;
    const int r = (i + 3) & 3;
    const int rate = 6 * (i + 1);

    const int tid = threadIdx.x;
    const int lane = tid & 63;
    const int w = tid >> 6;
    const int wo = w >> 1, wp = w & 1;          // o-quarter (64 rows), px-half (64 px)
    const int kg = lane >> 4, lm = lane & 15;
    const int pxS = tid >> 2, chgS = tid & 3;   // B staging: pixel, octet base
    const int oA = tid >> 3, partA = tid & 7;   // A staging: o-row, 16B part
    const int colA = (partA ^ (oA & 7)) * 8;    // sub0 col; sub1 = +64

    const unsigned short* xbh = x16h + (size_t)b * 1048576;
    const float* offb = off + (size_t)(r * 2 + b) * 18 * 4096;
    const unsigned short* wib = wTh + (size_t)i * 9 * 65536;

    for (int e = tid; e < 1152; e += 512) {
        int k = e >> 7, pl = e & 127;
        int pg = px0 + pl;
        int yy = pg >> 6, xc = pg & 63;
        float dy = offb[(size_t)(2 * k) * 4096 + pg];
        float dx = offb[(size_t)(2 * k + 1) * 4096 + pg];
        float py = (float)(yy + (k / 3 - 1) * rate) + dy;
        float pxf = (float)(xc + (k % 3 - 1) * rate) + dx;
        float fy = floorf(py), fx = floorf(pxf);
        int y0 = (int)fy, x0 = (int)fx;
        float wy = py - fy, wx = pxf - fx;
        float vy0 = ((unsigned)y0 < 64u) ? 1.f : 0.f;
        float vy1 = ((unsigned)(y0 + 1) < 64u) ? 1.f : 0.f;
        float vx0 = ((unsigned)x0 < 64u) ? 1.f : 0.f;
        float vx1 = ((unsigned)(x0 + 1) < 64u) ? 1.f : 0.f;
        int cy0 = min(max(y0, 0), 63), cy1 = min(max(y0 + 1, 0), 63);
        int cx0 = min(max(x0, 0), 63), cx1 = min(max(x0 + 1, 0), 63);
        s_pix[k][pl] = make_int4(cy0 * 64 + cx0, cy0 * 64 + cx1,
                                 cy1 * 64 + cx0, cy1 * 64 + cx1);
        s_wt[k][pl] = make_float4(vy0 * vx0 * (1.f - wy) * (1.f - wx),
                                  vy0 * vx1 * (1.f - wy) * wx,
                                  vy1 * vx0 * wy * (1.f - wx),
                                  vy1 * vx1 * wy * wx);
    }
    __syncthreads();

    f32x4 acc[4][4];
#pragma unroll
    for (int mi = 0; mi < 4; ++mi)
#pragma unroll
        for (int ni = 0; ni < 4; ++ni) acc[mi][ni] = (f32x4)(0.f);

    // in-flight state: A (2 subs x 4) + corners (2 subs x 2 regions x 4), all named
    uint4 aA0, aA1, aA2, aA3, aB0, aB1, aB2, aB3;
    uint4 c00, c01, c02, c03, c10, c11, c12, c13;   // sub0: oct chgS / chgS+4
    uint4 d00, d01, d02, d03, d10, d11, d12, d13;   // sub1

    // prologue: sub-steps 0 (tap0,c0=0) and 1 (tap0,c0=64)
    {
        const unsigned short* wr0 = wib + partA * 8;
        aA0 = *(const uint4*)(wr0 + (size_t)(oA      ) * 256);
        aA1 = *(const uint4*)(wr0 + (size_t)(oA +  64) * 256);
        aA2 = *(const uint4*)(wr0 + (size_t)(oA + 128) * 256);
        aA3 = *(const uint4*)(wr0 + (size_t)(oA + 192) * 256);
        const unsigned short* wr1 = wr0 + 64;
        aB0 = *(const uint4*)(wr1 + (size_t)(oA      ) * 256);
        aB1 = *(const uint4*)(wr1 + (size_t)(oA +  64) * 256);
        aB2 = *(const uint4*)(wr1 + (size_t)(oA + 128) * 256);
        aB3 = *(const uint4*)(wr1 + (size_t)(oA + 192) * 256);
        int4 p = s_pix[0][pxS];
        const unsigned short* x0p = xbh + chgS * 8;
        c00 = *(const uint4*)(x0p + ((size_t)p.x << 8));
        c01 = *(const uint4*)(x0p + ((size_t)p.y << 8));
        c02 = *(const uint4*)(x0p + ((size_t)p.z << 8));
        c03 = *(const uint4*)(x0p + ((size_t)p.w << 8));
        c10 = *(const uint4*)(x0p + ((size_t)p.x << 8) + 32);
        c11 = *(const uint4*)(x0p + ((size_t)p.y << 8) + 32);
        c12 = *(const uint4*)(x0p + ((size_t)p.z << 8) + 32);
        c13 = *(const uint4*)(x0p + ((size_t)p.w << 8) + 32);
        const unsigned short* x1p = x0p + 64;
        d00 = *(const uint4*)(x1p + ((size_t)p.x << 8));
        d01 = *(const uint4*)(x1p + ((size_t)p.y << 8));
        d02 = *(const uint4*)(x1p + ((size_t)p.z << 8));
        d03 = *(const uint4*)(x1p + ((size_t)p.w << 8));
        d10 = *(const uint4*)(x1p + ((size_t)p.x << 8) + 32);
        d11 = *(const uint4*)(x1p + ((size_t)p.y << 8) + 32);
        d12 = *(const uint4*)(x1p + ((size_t)p.z << 8) + 32);
        d13 = *(const uint4*)(x1p + ((size_t)p.w << 8) + 32);
    }

    for (int ph = 0; ph < 18; ++ph) {
        const int s0 = 2 * ph, s1 = 2 * ph + 1;
        const int tap0 = s0 >> 2, tap1 = s1 >> 2;

        // lerp both sub-steps (packed f16)
        uint4 pkA0, pkA1, pkB0, pkB1;
        {
            float4 q0 = s_wt[tap0][pxS];
            h2 qx = (h2)((_Float16)q0.x), qy = (h2)((_Float16)q0.y);
            h2 qz = (h2)((_Float16)q0.z), qv = (h2)((_Float16)q0.w);
            pkA0 = lerp4(c00, c01, c02, c03, qx, qy, qz, qv);
            pkA1 = lerp4(c10, c11, c12, c13, qx, qy, qz, qv);
            float4 q1 = s_wt[tap1][pxS];
            h2 rx = (h2)((_Float16)q1.x), ry = (h2)((_Float16)q1.y);
            h2 rz = (h2)((_Float16)q1.z), rv = (h2)((_Float16)q1.w);
            pkB0 = lerp4(d00, d01, d02, d03, rx, ry, rz, rv);
            pkB1 = lerp4(d10, d11, d12, d13, rx, ry, rz, rv);
        }

        LGKM_BARRIER();                 // prev phase's LDS reads done
        *(uint4*)&s_a[oA      ][colA]      = aA0;
        *(uint4*)&s_a[oA +  64][colA]      = aA1;
        *(uint4*)&s_a[oA + 128][colA]      = aA2;
        *(uint4*)&s_a[oA + 192][colA]      = aA3;
        *(uint4*)&s_a[oA      ][64 + colA] = aB0;
        *(uint4*)&s_a[oA +  64][64 + colA] = aB1;
        *(uint4*)&s_a[oA + 128][64 + colA] = aB2;
        *(uint4*)&s_a[oA + 192][64 + colA] = aB3;
        *(uint4*)&s_b[pxS][(chgS ^ (pxS & 7)) * 8]            = pkA0;
        *(uint4*)&s_b[pxS][((chgS + 4) ^ (pxS & 7)) * 8]      = pkA1;
        *(uint4*)&s_b[pxS][64 + (chgS ^ (pxS & 7)) * 8]       = pkB0;
        *(uint4*)&s_b[pxS][64 + ((chgS + 4) ^ (pxS & 7)) * 8] = pkB1;
        LGKM_BARRIER();                 // staging visible

        if (ph < 17) {                  // prefetch next phase's 2 sub-steps
            int n0 = s0 + 2, n1 = s0 + 3;
            int tA = n0 >> 2, cA = (n0 & 3) << 6;
            int tB = n1 >> 2, cB = (n1 & 3) << 6;
            const unsigned short* wr0 = wib + (size_t)tA * 65536 + cA + partA * 8;
            aA0 = *(const uint4*)(wr0 + (size_t)(oA      ) * 256);
            aA1 = *(const uint4*)(wr0 + (size_t)(oA +  64) * 256);
            aA2 = *(const uint4*)(wr0 + (size_t)(oA + 128) * 256);
            aA3 = *(const uint4*)(wr0 + (size_t)(oA + 192) * 256);
            const unsigned short* wr1 = wib + (size_t)tB * 65536 + cB + partA * 8;
            aB0 = *(const uint4*)(wr1 + (size_t)(oA      ) * 256);
            aB1 = *(const uint4*)(wr1 + (size_t)(oA +  64) * 256);
            aB2 = *(const uint4*)(wr1 + (size_t)(oA + 128) * 256);
            aB3 = *(const uint4*)(wr1 + (size_t)(oA + 192) * 256);
            int4 p0 = s_pix[tA][pxS];
            const unsigned short* x0p = xbh + cA + chgS * 8;
            c00 = *(const uint4*)(x0p + ((size_t)p0.x << 8));
            c01 = *(const uint4*)(x0p + ((size_t)p0.y << 8));
            c02 = *(const uint4*)(x0p + ((size_t)p0.z << 8));
            c03 = *(const uint4*)(x0p + ((size_t)p0.w << 8));
            c10 = *(const uint4*)(x0p + ((size_t)p0.x << 8) + 32);
            c11 = *(const uint4*)(x0p + ((size_t)p0.y << 8) + 32);
            c12 = *(const uint4*)(x0p + ((size_t)p0.z << 8) + 32);
            c13 = *(const uint4*)(x0p + ((size_t)p0.w << 8) + 32);
            int4 p1 = s_pix[tB][pxS];
            const unsigned short* x1p = xbh + cB + chgS * 8;
            d00 = *(const uint4*)(x1p + ((size_t)p1.x << 8));
            d01 = *(const uint4*)(x1p + ((size_t)p1.y << 8));
            d02 = *(const uint4*)(x1p + ((size_t)p1.z << 8));
            d03 = *(const uint4*)(x1p + ((size_t)p1.w << 8));
            d10 = *(const uint4*)(x1p + ((size_t)p1.x << 8) + 32);
            d11 = *(const uint4*)(x1p + ((size_t)p1.y << 8) + 32);
            d12 = *(const uint4*)(x1p + ((size_t)p1.z << 8) + 32);
            d13 = *(const uint4*)(x1p + ((size_t)p1.w << 8) + 32);
        }

        // MFMA: 2 subs x 2 kf x 4 mi x 4 ni = 64 per wave
#pragma unroll
        for (int sub = 0; sub < 2; ++sub) {
#pragma unroll
            for (int kf = 0; kf < 2; ++kf) {
                int oct = kf * 4 + kg;
                int col = sub * 64 + (oct ^ (lm & 7)) * 8;
                f16x8 bf0 = *(const f16x8*)&s_b[wp * 64 + lm][col];
                f16x8 bf1 = *(const f16x8*)&s_b[wp * 64 + 16 + lm][col];
                f16x8 bf2 = *(const f16x8*)&s_b[wp * 64 + 32 + lm][col];
                f16x8 bf3 = *(const f16x8*)&s_b[wp * 64 + 48 + lm][col];
#pragma unroll
                for (int mi = 0; mi < 4; ++mi) {
                    f16x8 af = *(const f16x8*)&s_a[wo * 64 + mi * 16 + lm][col];
                    acc[mi][0] = __builtin_amdgcn_mfma_f32_16x16x32_f16(af, bf0, acc[mi][0], 0, 0, 0);
                    acc[mi][1] = __builtin_amdgcn_mfma_f32_16x16x32_f16(af, bf1, acc[mi][1], 0, 0, 0);
                    acc[mi][2] = __builtin_amdgcn_mfma_f32_16x16x32_f16(af, bf2, acc[mi][2], 0, 0, 0);
                    acc[mi][3] = __builtin_amdgcn_mfma_f32_16x16x32_f16(af, bf3, acc[mi][3], 0, 0, 0);
                }
            }
        }
    }

    // epilogue: C/D col = lane&15 (px), row = kg*4 + reg (o)
    float* ob = out + ((size_t)b * 1024 + i * 256) * 4096;
#pragma unroll
    for (int mi = 0; mi < 4; ++mi) {
        int o = wo * 64 + mi * 16 + kg * 4;
#pragma unroll
        for (int ni = 0; ni < 4; ++ni) {
            int pg = px0 + wp * 64 + ni * 16 + lm;
#pragma unroll
            for (int reg = 0; reg < 4; ++reg)
                ob[(size_t)(o + reg) * 4096 + pg] = acc[mi][ni][reg];
        }
    }
}

extern "C" void kernel_launch(void* const* d_in, const int* in_sizes, int n_in,
                              void* d_out, int out_size, void* d_ws, size_t ws_size,
                              hipStream_t stream) {
    const float* x  = (const float*)d_in[0];   // [2,256,64,64]
    const float* dw = (const float*)d_in[1];   // [4,256,256,3,3]
    const float* ow = (const float*)d_in[2];   // [4,18,256,3,3]
    const float* ob = (const float*)d_in[3];   // [4,18]
    float* out = (float*)d_out;                // [2,1024,64,64]

    float* ws  = (float*)d_ws;
    float* off = ws;                                        // 589824 f32
    unsigned short* wTh  = (unsigned short*)(ws + 589824);  // 2359296 f16
    unsigned short* owTh = wTh + 2359296;                   // 294912 f16
    unsigned short* x16h = (unsigned short*)(ws + 1916928); // 2097152 f16 [b][pix][c]

    transpose_x_hwc_f16<<<512, 256, 0, stream>>>(x, x16h);
    transpose_dw_f16<<<1024, 256, 0, stream>>>(dw, wTh);
    transpose_ow_f16<<<1152, 256, 0, stream>>>(ow, owTh);
    offset_mfma3f<<<256, 512, 0, stream>>>(x16h, owTh, ob, off);
    deform_mfma11<<<256, 512, 0, stream>>>(x16h, wTh, off, out);
}